// Round 4
// baseline (159.063 us; speedup 1.0000x reference)
//
#include <hip/hip_runtime.h>
#include <math.h>

#define N_V 12288
#define D_F 32
#define N_E 196608
#define KNN 6
#define EPSF 1e-12f

#define SEGS 16
#define JSEG (N_V / SEGS)          // 768 candidate columns per segment
#define SUBTILES (JSEG / 16)       // 48 j-subtiles per segment
#define ROWS_PER_BLOCK 128         // 4 waves x 32 query rows
#define ROW_BLOCKS (N_V / ROWS_PER_BLOCK)  // 96 -> grid 96 x 16 = 1536 blocks

typedef __bf16 bf16x8 __attribute__((ext_vector_type(8)));
typedef float f32x4 __attribute__((ext_vector_type(4)));

static_assert(N_V % ROWS_PER_BLOCK == 0, "");
static_assert(SUBTILES % 4 == 0, "");

__device__ __forceinline__ unsigned short f2bf(float f) {
    unsigned u = __builtin_bit_cast(unsigned, f);
    unsigned r = u + 0x7fffu + ((u >> 16) & 1u);   // RNE
    return (unsigned short)(r >> 16);
}

// descending sorted 6-list insert: 1 max + 5 med3
__device__ __forceinline__ void ins6(float s[KNN], float nv) {
    float y0 = fmaxf(s[0], nv);
    float y1 = __builtin_amdgcn_fmed3f(s[0], s[1], nv);
    float y2 = __builtin_amdgcn_fmed3f(s[1], s[2], nv);
    float y3 = __builtin_amdgcn_fmed3f(s[2], s[3], nv);
    float y4 = __builtin_amdgcn_fmed3f(s[3], s[4], nv);
    float y5 = __builtin_amdgcn_fmed3f(s[4], s[5], nv);
    s[0] = y0; s[1] = y1; s[2] = y2; s[3] = y3; s[4] = y4; s[5] = y5;
}

// ---------- kernel 0: bf16 convert + msq(-0.5*sq) + zero merge counters ----------
__global__ __launch_bounds__(256) void prep_kernel(const float* __restrict__ x,
                                                   unsigned short* __restrict__ xb,
                                                   float* __restrict__ msq,
                                                   unsigned* __restrict__ cnt) {
    if (blockIdx.x == 0 && threadIdx.x < ROW_BLOCKS) cnt[threadIdx.x] = 0u;
    int i = blockIdx.x * 256 + threadIdx.x;
    if (i >= N_V) return;
    const float4* xr = (const float4*)(x + (size_t)i * D_F);
    float a0 = 0.f, a1 = 0.f, a2 = 0.f, a3 = 0.f;
    unsigned short h[D_F];
#pragma unroll
    for (int d = 0; d < 8; ++d) {
        float4 p = xr[d];
        a0 += p.x * p.x; a1 += p.y * p.y; a2 += p.z * p.z; a3 += p.w * p.w;
        h[4 * d + 0] = f2bf(p.x); h[4 * d + 1] = f2bf(p.y);
        h[4 * d + 2] = f2bf(p.z); h[4 * d + 3] = f2bf(p.w);
    }
    msq[i] = -0.5f * ((a0 + a1) + (a2 + a3));
    unsigned pk[16];
#pragma unroll
    for (int j = 0; j < 16; ++j)
        pk[j] = (unsigned)h[2 * j] | ((unsigned)h[2 * j + 1] << 16);
    uint4* dst = (uint4*)(xb + (size_t)i * D_F);
#pragma unroll
    for (int j = 0; j < 4; ++j)
        dst[j] = make_uint4(pk[4 * j], pk[4 * j + 1], pk[4 * j + 2], pk[4 * j + 3]);
}

// ---------- kernel 1: MFMA gram + per-row top-6 keys + fused cross-seg merge ----------
// A = candidate rows (j), B = query rows (i). C[m=quad*4+reg][n=l16]:
// lane's query row = rowbase + rt*16 + l16, candidates j = col0 + quad*4 + reg.
// acc init = msq[j] => C = dot - 0.5*sq_j (selection key; larger == closer).
__global__ __launch_bounds__(256, 6) void topk_fused(
    const unsigned short* __restrict__ xb, const float* __restrict__ msq,
    float* __restrict__ cand, unsigned* __restrict__ cnt,
    float* __restrict__ v, float* __restrict__ out) {
    __shared__ int sh_last;

    const int t = threadIdx.x;
    const int wave = t >> 6;
    const int lane = t & 63;
    const int quad = lane >> 4;
    const int l16 = lane & 15;

    const int rowbase = blockIdx.x * ROWS_PER_BLOCK + wave * 32;
    const int seg = blockIdx.y;
    const int j0 = seg * JSEG;

    // B fragments: query rows, register-resident
    bf16x8 bfrag[2];
#pragma unroll
    for (int rt = 0; rt < 2; ++rt)
        bfrag[rt] = *reinterpret_cast<const bf16x8*>(
            xb + (size_t)(rowbase + rt * 16 + l16) * D_F + quad * 8);

    float tk[2][KNN];
#pragma unroll
    for (int rt = 0; rt < 2; ++rt)
#pragma unroll
        for (int k = 0; k < KNN; ++k) tk[rt][k] = -3.0e38f;

    const unsigned short* aptr = xb + (size_t)(j0 + l16) * D_F + quad * 8;
    const float* mptr = msq + j0 + quad * 4;

    for (int it = 0; it < SUBTILES; it += 4) {
        bf16x8 a4[4];
        float4 m4[4];
#pragma unroll
        for (int u = 0; u < 4; ++u) {
            a4[u] = *reinterpret_cast<const bf16x8*>(aptr + (size_t)(it + u) * 16 * D_F);
            m4[u] = *reinterpret_cast<const float4*>(mptr + (it + u) * 16);
        }
#pragma unroll
        for (int u = 0; u < 4; ++u) {
            const f32x4 cinit = {m4[u].x, m4[u].y, m4[u].z, m4[u].w};
#pragma unroll
            for (int rt = 0; rt < 2; ++rt) {
                f32x4 c = __builtin_amdgcn_mfma_f32_16x16x32_bf16(a4[u], bfrag[rt], cinit, 0, 0, 0);
#pragma unroll
                for (int reg = 0; reg < 4; ++reg)
                    ins6(tk[rt], c[reg]);
            }
        }
    }

    // ---- cross-quad merge via shuffles (row's lists live in 4 quads, same l16) ----
#pragma unroll
    for (int rt = 0; rt < 2; ++rt) {
#pragma unroll
        for (int rnd = 0; rnd < 2; ++rnd) {
            const int mask = 16 << rnd;
            float b[KNN];
#pragma unroll
            for (int k = 0; k < KNN; ++k) b[k] = __shfl_xor(tk[rt][k], mask, 64);
#pragma unroll
            for (int k = 0; k < KNN; ++k) ins6(tk[rt], b[k]);
        }
    }

    if (quad == 0) {
#pragma unroll
        for (int rt = 0; rt < 2; ++rt) {
            const int g = rowbase + rt * 16 + l16;
            float* dst = cand + ((size_t)g * SEGS + seg) * KNN;
#pragma unroll
            for (int k = 0; k < KNN; ++k) dst[k] = tk[rt][k];
        }
    }

    // ---- last-arriving block for this row-group merges all segments ----
    __syncthreads();
    if (t == 0) {
        __threadfence();   // release our cand stores (device scope)
        unsigned old = atomicAdd(&cnt[blockIdx.x], 1u);
        sh_last = (old == SEGS - 1) ? 1 : 0;
    }
    __syncthreads();
    if (sh_last) {
        __threadfence();   // acquire other blocks' cand stores
        const int row = t >> 1;            // 0..127
        const int half = t & 1;
        const int g = blockIdx.x * ROWS_PER_BLOCK + row;
        const float4* c = (const float4*)(cand + (size_t)g * (SEGS * KNN) + half * 48);
        float mk[KNN];
#pragma unroll
        for (int k = 0; k < KNN; ++k) mk[k] = -3.0e38f;
#pragma unroll
        for (int s4 = 0; s4 < 12; ++s4) {
            float4 q = c[s4];
            ins6(mk, q.x); ins6(mk, q.y); ins6(mk, q.z); ins6(mk, q.w);
        }
        // combine the two halves (adjacent lanes in same wave)
        float b[KNN];
#pragma unroll
        for (int k = 0; k < KNN; ++k) b[k] = __shfl_xor(mk[k], 1, 64);
#pragma unroll
        for (int k = 0; k < KNN; ++k) ins6(mk, b[k]);
        if (half == 0) {
            const float msqi = msq[g];
            float ssum = 0.f;
#pragma unroll
            for (int m = 1; m < KNN; ++m) {
                const float d2 = -2.0f * (mk[m] + msqi);   // sq_i - 2*key
                ssum += expf(-sqrtf(fmaxf(d2, EPSF)));
            }
            const float vi = 1.0f - ssum / (float)KNN;
            v[g] = vi;
            out[2 * g] = vi;
            out[2 * g + 1] = 0.0f;
        }
    }
}

// ---------- kernel 2: edge filtration ----------
__global__ __launch_bounds__(256) void edge_kernel(const float* __restrict__ x,
                                                   const int* __restrict__ ei,
                                                   const float* __restrict__ v,
                                                   float* __restrict__ out) {
    int e = blockIdx.x * 256 + threadIdx.x;
    if (e >= N_E) return;
    const int u = ei[e];
    const int w = ei[N_E + e];
    const float4* xu = (const float4*)(x + (size_t)u * D_F);
    const float4* xw = (const float4*)(x + (size_t)w * D_F);
    float a0 = 0.f, a1 = 0.f, a2 = 0.f, a3 = 0.f;
#pragma unroll
    for (int d = 0; d < 8; ++d) {
        float4 p = xu[d], q = xw[d];
        float dx = p.x - q.x, dy = p.y - q.y, dz = p.z - q.z, dw = p.w - q.w;
        a0 += dx * dx; a1 += dy * dy; a2 += dz * dz; a3 += dw * dw;
    }
    const float enorm = sqrtf(fmaxf((a0 + a1) + (a2 + a3), EPSF));
    const float ey = 1.0f - expf(-enorm);
    const float ev = fmaxf(v[u], v[w]);
    out[2 * (N_V + e) + 0] = ev;
    out[2 * (N_V + e) + 1] = ey;
}

extern "C" void kernel_launch(void* const* d_in, const int* in_sizes, int n_in,
                              void* d_out, int out_size, void* d_ws, size_t ws_size,
                              hipStream_t stream) {
    const float* x = (const float*)d_in[0];
    const int* ei = (const int*)d_in[1];
    float* out = (float*)d_out;
    char* ws = (char*)d_ws;

    unsigned short* xb = (unsigned short*)ws;                  // 786432 B
    float* msq = (float*)(ws + 786432);                        // 49152 B
    float* v   = (float*)(ws + 786432 + 49152);                // 49152 B
    float* cand = (float*)(ws + 786432 + 2 * 49152);           // 4718592 B
    unsigned* cnt = (unsigned*)(ws + 786432 + 2 * 49152 + 4718592);  // 384 B

    prep_kernel<<<(N_V + 255) / 256, 256, 0, stream>>>(x, xb, msq, cnt);

    dim3 g1(ROW_BLOCKS, SEGS);
    topk_fused<<<g1, 256, 0, stream>>>(xb, msq, cand, cnt, v, out);

    edge_kernel<<<N_E / 256, 256, 0, stream>>>(x, ei, v, out);
}

// Round 5
// 115.033 us; speedup vs baseline: 1.3828x; 1.3828x over previous
//
#include <hip/hip_runtime.h>
#include <math.h>

#define N_V 12288
#define D_F 32
#define N_E 196608
#define KNN 6
#define EPSF 1e-12f

#define SEGS 16
#define JSEG (N_V / SEGS)          // 768 candidate columns per segment
#define SUBTILES (JSEG / 16)       // 48 j-subtiles per segment
#define ROWS_PER_BLOCK 128         // 4 waves x 32 query rows
#define ROW_BLOCKS (N_V / ROWS_PER_BLOCK)  // 96 -> grid 96 x 16 = 1536 blocks

typedef __bf16 bf16x8 __attribute__((ext_vector_type(8)));
typedef float f32x4 __attribute__((ext_vector_type(4)));

static_assert(N_V % ROWS_PER_BLOCK == 0, "");
static_assert(SUBTILES % 4 == 0, "");

__device__ __forceinline__ unsigned short f2bf(float f) {
    unsigned u = __builtin_bit_cast(unsigned, f);
    unsigned r = u + 0x7fffu + ((u >> 16) & 1u);   // RNE
    return (unsigned short)(r >> 16);
}

// descending sorted 6-list insert: 1 max + 5 med3
__device__ __forceinline__ void ins6(float s[KNN], float nv) {
    float y0 = fmaxf(s[0], nv);
    float y1 = __builtin_amdgcn_fmed3f(s[0], s[1], nv);
    float y2 = __builtin_amdgcn_fmed3f(s[1], s[2], nv);
    float y3 = __builtin_amdgcn_fmed3f(s[2], s[3], nv);
    float y4 = __builtin_amdgcn_fmed3f(s[3], s[4], nv);
    float y5 = __builtin_amdgcn_fmed3f(s[4], s[5], nv);
    s[0] = y0; s[1] = y1; s[2] = y2; s[3] = y3; s[4] = y4; s[5] = y5;
}

// ---------- kernel 0: bf16 convert + msq(-0.5*sq), 8 threads/row ----------
__global__ __launch_bounds__(256) void prep_kernel(const float* __restrict__ x,
                                                   unsigned short* __restrict__ xb,
                                                   float* __restrict__ msq) {
    const int gid = blockIdx.x * 256 + threadIdx.x;   // 0..98303
    const int row = gid >> 3;
    const int h = gid & 7;
    float4 p = ((const float4*)(x + (size_t)row * D_F))[h];
    float s = p.x * p.x + p.y * p.y + p.z * p.z + p.w * p.w;
    s += __shfl_xor(s, 1, 64);
    s += __shfl_xor(s, 2, 64);
    s += __shfl_xor(s, 4, 64);
    const unsigned lo = (unsigned)f2bf(p.x) | ((unsigned)f2bf(p.y) << 16);
    const unsigned hi = (unsigned)f2bf(p.z) | ((unsigned)f2bf(p.w) << 16);
    ((uint2*)xb)[gid] = make_uint2(lo, hi);
    if (h == 0) msq[row] = -0.5f * s;
}

// ---------- kernel 1: MFMA gram + per-row top-6 keys ----------
// A = candidate rows (j), B = query rows (i). C[m=quad*4+reg][n=l16]:
// lane's query row = rowbase + rt*16 + l16, candidates j = col0 + quad*4 + reg.
// acc init = msq[j] => C = dot - 0.5*sq_j (selection key; larger == closer).
__global__ __launch_bounds__(256, 6) void topk_mfma(
    const unsigned short* __restrict__ xb, const float* __restrict__ msq,
    float* __restrict__ cand) {
    const int t = threadIdx.x;
    const int wave = t >> 6;
    const int lane = t & 63;
    const int quad = lane >> 4;
    const int l16 = lane & 15;

    const int rowbase = blockIdx.x * ROWS_PER_BLOCK + wave * 32;
    const int seg = blockIdx.y;
    const int j0 = seg * JSEG;

    // B fragments: query rows, register-resident
    bf16x8 bfrag[2];
#pragma unroll
    for (int rt = 0; rt < 2; ++rt)
        bfrag[rt] = *reinterpret_cast<const bf16x8*>(
            xb + (size_t)(rowbase + rt * 16 + l16) * D_F + quad * 8);

    float tk[2][KNN];
#pragma unroll
    for (int rt = 0; rt < 2; ++rt)
#pragma unroll
        for (int k = 0; k < KNN; ++k) tk[rt][k] = -3.0e38f;

    const unsigned short* aptr = xb + (size_t)(j0 + l16) * D_F + quad * 8;
    const float* mptr = msq + j0 + quad * 4;

    for (int it = 0; it < SUBTILES; it += 4) {
#pragma unroll
        for (int u = 0; u < 4; ++u) {
            const bf16x8 a = *reinterpret_cast<const bf16x8*>(aptr + u * (16 * D_F));
            const float4 m = *reinterpret_cast<const float4*>(mptr + u * 16);
            const f32x4 cinit = {m.x, m.y, m.z, m.w};
#pragma unroll
            for (int rt = 0; rt < 2; ++rt) {
                f32x4 c = __builtin_amdgcn_mfma_f32_16x16x32_bf16(a, bfrag[rt], cinit, 0, 0, 0);
#pragma unroll
                for (int reg = 0; reg < 4; ++reg)
                    ins6(tk[rt], c[reg]);
            }
        }
        aptr += 4 * 16 * D_F;
        mptr += 4 * 16;
    }

    // ---- cross-quad merge via shuffles (row's lists live in 4 quads, same l16) ----
#pragma unroll
    for (int rt = 0; rt < 2; ++rt) {
#pragma unroll
        for (int rnd = 0; rnd < 2; ++rnd) {
            const int mask = 16 << rnd;
            float b[KNN];
#pragma unroll
            for (int k = 0; k < KNN; ++k) b[k] = __shfl_xor(tk[rt][k], mask, 64);
#pragma unroll
            for (int k = 0; k < KNN; ++k) ins6(tk[rt], b[k]);
        }
    }

    if (quad == 0) {
#pragma unroll
        for (int rt = 0; rt < 2; ++rt) {
            const int g = rowbase + rt * 16 + l16;
            float* dst = cand + ((size_t)g * SEGS + seg) * KNN;
#pragma unroll
            for (int k = 0; k < KNN; ++k) dst[k] = tk[rt][k];
        }
    }
}

// ---------- kernel 2: merge per-segment keys -> v, 4 threads/row ----------
__global__ __launch_bounds__(256) void merge_v(const float* __restrict__ cand,
                                               const float* __restrict__ msq,
                                               float* __restrict__ v,
                                               float* __restrict__ out) {
    const int gid = blockIdx.x * 256 + threadIdx.x;   // 0..49151
    const int row = gid >> 2;
    const int h = gid & 3;
    const float4* c = (const float4*)(cand + (size_t)row * (SEGS * KNN));  // 24 x float4
    float mk[KNN];
#pragma unroll
    for (int k = 0; k < KNN; ++k) mk[k] = -3.0e38f;
#pragma unroll
    for (int s4 = 0; s4 < 6; ++s4) {
        float4 q = c[s4 * 4 + h];
        ins6(mk, q.x); ins6(mk, q.y); ins6(mk, q.z); ins6(mk, q.w);
    }
    // merge across the 4 lanes of this row (consecutive lanes, same wave)
#pragma unroll
    for (int rnd = 0; rnd < 2; ++rnd) {
        const int mask = 1 << rnd;
        float b[KNN];
#pragma unroll
        for (int k = 0; k < KNN; ++k) b[k] = __shfl_xor(mk[k], mask, 64);
#pragma unroll
        for (int k = 0; k < KNN; ++k) ins6(mk, b[k]);
    }
    if (h == 0) {
        const float msqi = msq[row];
        float ssum = 0.f;
#pragma unroll
        for (int m = 1; m < KNN; ++m) {
            const float d2 = -2.0f * (mk[m] + msqi);   // sq_i - 2*key
            ssum += expf(-sqrtf(fmaxf(d2, EPSF)));
        }
        const float vi = 1.0f - ssum / (float)KNN;
        v[row] = vi;
        out[2 * row] = vi;
        out[2 * row + 1] = 0.0f;
    }
}

// ---------- kernel 3: edge filtration ----------
__global__ __launch_bounds__(256) void edge_kernel(const float* __restrict__ x,
                                                   const int* __restrict__ ei,
                                                   const float* __restrict__ v,
                                                   float* __restrict__ out) {
    int e = blockIdx.x * 256 + threadIdx.x;
    if (e >= N_E) return;
    const int u = ei[e];
    const int w = ei[N_E + e];
    const float4* xu = (const float4*)(x + (size_t)u * D_F);
    const float4* xw = (const float4*)(x + (size_t)w * D_F);
    float a0 = 0.f, a1 = 0.f, a2 = 0.f, a3 = 0.f;
#pragma unroll
    for (int d = 0; d < 8; ++d) {
        float4 p = xu[d], q = xw[d];
        float dx = p.x - q.x, dy = p.y - q.y, dz = p.z - q.z, dw = p.w - q.w;
        a0 += dx * dx; a1 += dy * dy; a2 += dz * dz; a3 += dw * dw;
    }
    const float enorm = sqrtf(fmaxf((a0 + a1) + (a2 + a3), EPSF));
    const float ey = 1.0f - expf(-enorm);
    const float ev = fmaxf(v[u], v[w]);
    out[2 * (N_V + e) + 0] = ev;
    out[2 * (N_V + e) + 1] = ey;
}

extern "C" void kernel_launch(void* const* d_in, const int* in_sizes, int n_in,
                              void* d_out, int out_size, void* d_ws, size_t ws_size,
                              hipStream_t stream) {
    const float* x = (const float*)d_in[0];
    const int* ei = (const int*)d_in[1];
    float* out = (float*)d_out;
    char* ws = (char*)d_ws;

    unsigned short* xb = (unsigned short*)ws;                  // 786432 B
    float* msq = (float*)(ws + 786432);                        // 49152 B
    float* v   = (float*)(ws + 786432 + 49152);                // 49152 B
    float* cand = (float*)(ws + 786432 + 2 * 49152);           // 4718592 B

    prep_kernel<<<(N_V * 8) / 256, 256, 0, stream>>>(x, xb, msq);

    dim3 g1(ROW_BLOCKS, SEGS);
    topk_mfma<<<g1, 256, 0, stream>>>(xb, msq, cand);

    merge_v<<<(N_V * 4) / 256, 256, 0, stream>>>(cand, msq, v, out);

    edge_kernel<<<N_E / 256, 256, 0, stream>>>(x, ei, v, out);
}